// Round 1
// baseline (260.553 us; speedup 1.0000x reference)
//
#include <hip/hip_runtime.h>
#include <cstddef>

// Sizes (fixed per reference):
// B=8192, D=784, H=256, E=32, K=512
#define NB 8192
#define ND 784
#define NH 256
#define NE 32
#define NK 512
#define ALPHA_F 1000.0f

// ---------------------------------------------------------------------------
// Generic fp32 GEMM: C[M,N] = op(A[M,K] @ W[K,N] + bias), op = relu or id.
// BM=128, BN=64, BK=16, 256 threads, 8x4 outputs/thread, register prefetch.
// Requires: M % 128 == 0, K % 16 == 0, N % 4 == 0 (N edge guarded).
// ---------------------------------------------------------------------------
template<bool RELU>
__global__ __launch_bounds__(256)
void gemm_kernel(const float* __restrict__ A, const float* __restrict__ W,
                 const float* __restrict__ bias, float* __restrict__ C,
                 int M, int N, int K) {
    __shared__ float As[16][128];   // transposed: As[k][m]
    __shared__ float Bs[16][64];    // Bs[k][n]

    const int tid = threadIdx.x;
    const int bm  = blockIdx.x * 128;
    const int bn  = blockIdx.y * 64;
    const int tx  = tid & 15;   // n-dir, 4 cols
    const int ty  = tid >> 4;   // m-dir, 8 rows

    // A staging: thread loads 8 consecutive k's of one row (2 float4)
    const int arow = tid >> 1;
    const int ak   = (tid & 1) * 8;
    // B staging: thread loads float4 of one k-row
    const int brow = tid >> 4;
    const int bcol = (tid & 15) * 4;

    const float* aptr = A + (size_t)(bm + arow) * K + ak;
    const int gcol = bn + bcol;
    const bool bvalid = (gcol < N);
    const float* wptr = W + (size_t)brow * N + (bvalid ? gcol : 0);

    // prefetch tile 0
    float4 a0 = *(const float4*)(aptr);
    float4 a1 = *(const float4*)(aptr + 4);
    float4 bv = bvalid ? *(const float4*)(wptr) : make_float4(0.f, 0.f, 0.f, 0.f);

    float acc[8][4];
    #pragma unroll
    for (int i = 0; i < 8; ++i)
        #pragma unroll
        for (int j = 0; j < 4; ++j) acc[i][j] = 0.f;

    for (int k0 = 0; k0 < K; k0 += 16) {
        // commit staged regs to LDS
        As[ak + 0][arow] = a0.x; As[ak + 1][arow] = a0.y;
        As[ak + 2][arow] = a0.z; As[ak + 3][arow] = a0.w;
        As[ak + 4][arow] = a1.x; As[ak + 5][arow] = a1.y;
        As[ak + 6][arow] = a1.z; As[ak + 7][arow] = a1.w;
        *(float4*)&Bs[brow][bcol] = bv;
        __syncthreads();

        // prefetch next tile while computing this one
        const int k1 = k0 + 16;
        if (k1 < K) {
            a0 = *(const float4*)(aptr + k1);
            a1 = *(const float4*)(aptr + k1 + 4);
            bv = bvalid ? *(const float4*)(wptr + (size_t)k1 * N)
                        : make_float4(0.f, 0.f, 0.f, 0.f);
        }

        #pragma unroll
        for (int kk = 0; kk < 16; ++kk) {
            float4 av0 = *(float4*)&As[kk][ty * 8];
            float4 av1 = *(float4*)&As[kk][ty * 8 + 4];
            float4 bb  = *(float4*)&Bs[kk][tx * 4];
            float a[8] = {av0.x, av0.y, av0.z, av0.w, av1.x, av1.y, av1.z, av1.w};
            float b[4] = {bb.x, bb.y, bb.z, bb.w};
            #pragma unroll
            for (int i = 0; i < 8; ++i)
                #pragma unroll
                for (int j = 0; j < 4; ++j)
                    acc[i][j] = fmaf(a[i], b[j], acc[i][j]);
        }
        __syncthreads();
    }

    // epilogue
    const int gn = bn + tx * 4;
    if (gn < N) {
        float4 bb4 = *(const float4*)(bias + gn);
        #pragma unroll
        for (int i = 0; i < 8; ++i) {
            const int gm = bm + ty * 8 + i;
            float4 v;
            v.x = acc[i][0] + bb4.x;
            v.y = acc[i][1] + bb4.y;
            v.z = acc[i][2] + bb4.z;
            v.w = acc[i][3] + bb4.w;
            if (RELU) {
                v.x = fmaxf(v.x, 0.f); v.y = fmaxf(v.y, 0.f);
                v.z = fmaxf(v.z, 0.f); v.w = fmaxf(v.w, 0.f);
            }
            *(float4*)(C + (size_t)gm * N + gn) = v;
        }
    }
}

// ---------------------------------------------------------------------------
// emb[B,32] = h[B,256] @ W2[256,32] + b2.  Block = 8 rows x 32 cols.
// ---------------------------------------------------------------------------
__global__ __launch_bounds__(256)
void emb_kernel(const float* __restrict__ h, const float* __restrict__ W2,
                const float* __restrict__ b2, float* __restrict__ emb) {
    const int tid = threadIdx.x;
    const int col = tid & 31;
    const int row = blockIdx.x * 8 + (tid >> 5);
    const float* hrow = h + (size_t)row * NH;
    float acc0 = 0.f, acc1 = 0.f;
    #pragma unroll 4
    for (int k = 0; k < NH; k += 4) {
        float4 hv = *(const float4*)(hrow + k);
        acc0 = fmaf(hv.x, W2[(k + 0) * NE + col], acc0);
        acc1 = fmaf(hv.y, W2[(k + 1) * NE + col], acc1);
        acc0 = fmaf(hv.z, W2[(k + 2) * NE + col], acc0);
        acc1 = fmaf(hv.w, W2[(k + 3) * NE + col], acc1);
    }
    emb[(size_t)row * NE + col] = acc0 + acc1 + b2[col];
}

// ---------------------------------------------------------------------------
// h2[B,256] = relu(emb[B,32] @ W3[32,256] + b3). Block = 8 rows x 256 cols.
// ---------------------------------------------------------------------------
__global__ __launch_bounds__(256)
void h2_kernel(const float* __restrict__ emb, const float* __restrict__ W3,
               const float* __restrict__ b3, float* __restrict__ h2) {
    __shared__ float es[8][32];
    const int tid = threadIdx.x;
    const int r0  = blockIdx.x * 8;
    es[tid >> 5][tid & 31] = emb[(size_t)r0 * NE + tid];
    __syncthreads();
    const int col = tid;
    float acc[8];
    #pragma unroll
    for (int r = 0; r < 8; ++r) acc[r] = 0.f;
    #pragma unroll
    for (int k = 0; k < NE; ++k) {
        float w = W3[k * NH + col];
        #pragma unroll
        for (int r = 0; r < 8; ++r) acc[r] = fmaf(es[r][k], w, acc[r]);
    }
    const float bb = b3[col];
    #pragma unroll
    for (int r = 0; r < 8; ++r) {
        float v = acc[r] + bb;
        h2[(size_t)(r0 + r) * NH + col] = v > 0.f ? v : 0.f;
    }
}

// ---------------------------------------------------------------------------
// Distances + stable softmin. Block = 8 rows, 256 threads.
// reps staged into LDS in 2 chunks of 256 clusters (pad stride 36 floats).
// Thread t owns clusters t and 256+t for all 8 rows.
// ---------------------------------------------------------------------------
__global__ __launch_bounds__(256)
void dist_kernel(const float* __restrict__ emb, const float* __restrict__ reps,
                 float* __restrict__ dist, float* __restrict__ wout) {
    __shared__ float reps_s[256 * 36];
    __shared__ float emb_s[8][32];
    __shared__ float smin[8][4];
    __shared__ float ssum[8][4];
    __shared__ float rowmin[8];
    __shared__ float rowsum[8];

    const int tid = threadIdx.x;
    const int r0  = blockIdx.x * 8;
    emb_s[tid >> 5][tid & 31] = emb[(size_t)r0 * NE + tid];

    float d[2][8];
    #pragma unroll
    for (int ch = 0; ch < 2; ++ch) {
        __syncthreads();  // emb_s ready (ch=0) / reps_s reuse safe (ch=1)
        for (int i = tid; i < 256 * 32; i += 256) {
            reps_s[(i >> 5) * 36 + (i & 31)] = reps[ch * 8192 + i];
        }
        __syncthreads();
        float4 rv[8];
        #pragma unroll
        for (int e4 = 0; e4 < 8; ++e4)
            rv[e4] = *(float4*)&reps_s[tid * 36 + e4 * 4];
        #pragma unroll
        for (int r = 0; r < 8; ++r) {
            float acc = 0.f;
            #pragma unroll
            for (int e4 = 0; e4 < 8; ++e4) {
                float4 ev = *(float4*)&emb_s[r][e4 * 4];
                float t0 = ev.x - rv[e4].x; acc = fmaf(t0, t0, acc);
                float t1 = ev.y - rv[e4].y; acc = fmaf(t1, t1, acc);
                float t2 = ev.z - rv[e4].z; acc = fmaf(t2, t2, acc);
                float t3 = ev.w - rv[e4].w; acc = fmaf(t3, t3, acc);
            }
            d[ch][r] = acc;
        }
    }

    const int lane = tid & 63;
    const int wid  = tid >> 6;

    // per-row block-wide min
    #pragma unroll
    for (int r = 0; r < 8; ++r) {
        float m = fminf(d[0][r], d[1][r]);
        #pragma unroll
        for (int off = 32; off > 0; off >>= 1)
            m = fminf(m, __shfl_xor(m, off, 64));
        if (lane == 0) smin[r][wid] = m;
    }
    __syncthreads();
    if (tid < 8)
        rowmin[tid] = fminf(fminf(smin[tid][0], smin[tid][1]),
                            fminf(smin[tid][2], smin[tid][3]));
    __syncthreads();

    // exponentials + block-wide sum
    float e0[8], e1[8];
    #pragma unroll
    for (int r = 0; r < 8; ++r) {
        const float mm = rowmin[r];
        e0[r] = expf(-ALPHA_F * (d[0][r] - mm));
        e1[r] = expf(-ALPHA_F * (d[1][r] - mm));
        float s = e0[r] + e1[r];
        #pragma unroll
        for (int off = 32; off > 0; off >>= 1)
            s += __shfl_xor(s, off, 64);
        if (lane == 0) ssum[r][wid] = s;
    }
    __syncthreads();
    if (tid < 8)
        rowsum[tid] = (ssum[tid][0] + ssum[tid][1]) + (ssum[tid][2] + ssum[tid][3]);
    __syncthreads();

    #pragma unroll
    for (int r = 0; r < 8; ++r) {
        const size_t row = (size_t)(r0 + r);
        const float inv = 1.0f / rowsum[r];
        dist[row * NK + tid]       = d[0][r];
        dist[row * NK + 256 + tid] = d[1][r];
        wout[row * NK + tid]       = d[0][r] * (e0[r] * inv);
        wout[row * NK + 256 + tid] = d[1][r] * (e1[r] * inv);
    }
}

// ---------------------------------------------------------------------------
extern "C" void kernel_launch(void* const* d_in, const int* in_sizes, int n_in,
                              void* d_out, int out_size, void* d_ws, size_t ws_size,
                              hipStream_t stream) {
    const float* x    = (const float*)d_in[0];
    const float* reps = (const float*)d_in[1];
    const float* W1   = (const float*)d_in[2];
    const float* b1   = (const float*)d_in[3];
    const float* W2   = (const float*)d_in[4];
    const float* b2   = (const float*)d_in[5];
    const float* W3   = (const float*)d_in[6];
    const float* b3   = (const float*)d_in[7];
    const float* W4   = (const float*)d_in[8];
    const float* b4   = (const float*)d_in[9];

    float* out   = (float*)d_out;
    float* wout  = out;                              // [8192,512]
    float* dist  = out + (size_t)NB * NK;            // [8192,512]
    float* recon = out + (size_t)2 * NB * NK;        // [8192,784]
    float* emb   = out + (size_t)2 * NB * NK + (size_t)NB * ND;  // [8192,32]

    // Scratch inside d_out regions that are only written by the LAST kernel:
    // h  (8192x256) lives in the distances region (written by dist_kernel),
    // h2 (8192x256) lives in the weighted region  (written by dist_kernel).
    float* h  = dist;
    float* h2 = wout;

    // 1) h = relu(x @ W1 + b1)            [8192,256], K=784
    gemm_kernel<true><<<dim3(64, 4), 256, 0, stream>>>(x, W1, b1, h, NB, NH, ND);
    // 2) emb = h @ W2 + b2                [8192,32], K=256
    emb_kernel<<<NB / 8, 256, 0, stream>>>(h, W2, b2, emb);
    // 3) h2 = relu(emb @ W3 + b3)         [8192,256], K=32
    h2_kernel<<<NB / 8, 256, 0, stream>>>(emb, W3, b3, h2);
    // 4) recon = h2 @ W4 + b4             [8192,784], K=256
    gemm_kernel<false><<<dim3(64, 13), 256, 0, stream>>>(h2, W4, b4, recon, NB, ND, NH);
    // 5) distances + softmin              [8192,512]
    dist_kernel<<<NB / 8, 256, 0, stream>>>(emb, reps, dist, wout);
}